// Round 2
// baseline (1428.485 us; speedup 1.0000x reference)
//
#include <hip/hip_runtime.h>

#define Bsz 4
#define Cin 64
#define C2c 128
#define Hh 256
#define Ww 256
#define Tt 16
#define HW (Hh*Ww)
#define ICC 8

// ---------- Wt[t*4+o][c] = W_out[o][c] * masks[t][c] ----------
__global__ void wt_kernel(const float* __restrict__ W_out,
                          const float* __restrict__ masks,
                          float* __restrict__ Wt) {
  int i = blockIdx.x * 256 + threadIdx.x;           // 8192 total
  if (i < Tt * 4 * C2c) {
    int to = i >> 7, c = i & 127;
    int t = to >> 2, o = to & 3;
    Wt[i] = W_out[o * C2c + c] * masks[t * C2c + c];
  }
}

// ---------- conv1: x[b,64,H,W] -> h[bi,128,H,W] ----------
// grid (W/32, H/32, nb*8 oc-chunks), block 256 (32x8), 4 rows/thread, 16 oc/block
// launch_bounds(256,4): 4 blocks/CU -> 128-VGPR budget so acc[16][4] stays in VGPRs
// (R1: default bounds gave 64 VGPRs -> acc in AGPRs -> 3 VALU ops per FMA, 23% FLOP eff)
__global__ __launch_bounds__(256, 4) void conv1_kernel(
    const float* __restrict__ x, const float* __restrict__ Wc,
    const float* __restrict__ bc, float* __restrict__ h, int b0) {
  __shared__ float xt[ICC][34 * 34];
  const int tid = threadIdx.x;
  const int tx = tid & 31, ty = tid >> 5;
  const int x0 = blockIdx.x * 32, y0 = blockIdx.y * 32;
  const int oc0 = (blockIdx.z & 7) * 16;
  const int bi = blockIdx.z >> 3;
  const float* xb = x + (size_t)(b0 + bi) * Cin * HW;

  float acc[16][4];
  #pragma unroll
  for (int o = 0; o < 16; ++o)
    #pragma unroll
    for (int r = 0; r < 4; ++r) acc[o][r] = 0.f;

  #pragma unroll 1
  for (int icc = 0; icc < Cin; icc += ICC) {
    __syncthreads();
    // staged loads: thread (tx,ty) covers rows ty, ty+8, ty+16, ty+24, (+32 if ty<2),
    // cols tx and tx+32 (tx<2). Cheap address math, coalesced rows.
    #pragma unroll
    for (int icl = 0; icl < ICC; ++icl) {
      const float* src = xb + (size_t)(icc + icl) * HW;
      for (int r = ty; r < 34; r += 8) {
        int gy = y0 - 1 + r;
        int gx0 = x0 - 1 + tx;
        float v0 = ((unsigned)gy < Hh && (unsigned)gx0 < Ww) ? src[(size_t)gy * Ww + gx0] : 0.f;
        xt[icl][r * 34 + tx] = v0;
        if (tx < 2) {
          int gx1 = gx0 + 32;
          float v1 = ((unsigned)gy < Hh && (unsigned)gx1 < Ww) ? src[(size_t)gy * Ww + gx1] : 0.f;
          xt[icl][r * 34 + tx + 32] = v1;
        }
      }
    }
    __syncthreads();
    #pragma unroll 2
    for (int icl = 0; icl < ICC; ++icl) {
      float xv[6][3];
      #pragma unroll
      for (int rr = 0; rr < 6; ++rr)
        #pragma unroll
        for (int cc = 0; cc < 3; ++cc)
          xv[rr][cc] = xt[icl][(ty * 4 + rr) * 34 + tx + cc];
      const float* wp = Wc + ((size_t)oc0 * Cin + (icc + icl)) * 9;
      #pragma unroll
      for (int o = 0; o < 16; ++o) {
        float w[9];
        #pragma unroll
        for (int k = 0; k < 9; ++k) w[k] = wp[(size_t)o * Cin * 9 + k];  // block-uniform -> s_load
        #pragma unroll
        for (int r = 0; r < 4; ++r) {
          float s = acc[o][r];
          #pragma unroll
          for (int k = 0; k < 9; ++k)
            s = fmaf(w[k], xv[r + k / 3][k % 3], s);
          acc[o][r] = s;
        }
      }
    }
  }
  float* hb = h + (size_t)bi * C2c * HW;
  #pragma unroll
  for (int o = 0; o < 16; ++o) {
    float bias = bc[oc0 + o];
    #pragma unroll
    for (int r = 0; r < 4; ++r)
      hb[(size_t)(oc0 + o) * HW + (size_t)(y0 + ty * 4 + r) * Ww + x0 + tx] = acc[o][r] + bias;
  }
}

// ---------- stage2: samples GEMV + stats + AU conv, fused ----------
// grid (W/32, H/8, nb), block 256 (32x8), 1 pixel/thread
__global__ __launch_bounds__(256, 4) void stage2_kernel(
    const float* __restrict__ h, const float* __restrict__ Wt,
    const float* __restrict__ b_out, const float* __restrict__ W_aue,
    const float* __restrict__ b_aue, const float* __restrict__ lms,
    float* __restrict__ out, int b0) {
  __shared__ float ht[ICC][10 * 34];
  const int tid = threadIdx.x;
  const int tx = tid & 31, ty = tid >> 5;
  const int x0 = blockIdx.x * 32, y0 = blockIdx.y * 8;
  const int bi = blockIdx.z;
  const int b = b0 + bi;
  const float* hb = h + (size_t)bi * C2c * HW;
  const int px = x0 + tx, py = y0 + ty;

  float accs[64];
  #pragma unroll
  for (int i = 0; i < 64; ++i) accs[i] = 0.f;
  float accA[4] = {0.f, 0.f, 0.f, 0.f};

  #pragma unroll 1
  for (int icc = 0; icc < C2c; icc += ICC) {
    __syncthreads();
    #pragma unroll
    for (int icl = 0; icl < ICC; ++icl) {
      const float* src = hb + (size_t)(icc + icl) * HW;
      for (int r = ty; r < 10; r += 8) {
        int gy = y0 - 1 + r;
        int gx0 = x0 - 1 + tx;
        float v0 = ((unsigned)gy < Hh && (unsigned)gx0 < Ww) ? src[(size_t)gy * Ww + gx0] : 0.f;
        ht[icl][r * 34 + tx] = v0;
        if (tx < 2) {
          int gx1 = gx0 + 32;
          float v1 = ((unsigned)gy < Hh && (unsigned)gx1 < Ww) ? src[(size_t)gy * Ww + gx1] : 0.f;
          ht[icl][r * 34 + tx + 32] = v1;
        }
      }
    }
    __syncthreads();
    float xh[ICC];
    #pragma unroll
    for (int icl = 0; icl < ICC; ++icl)
      xh[icl] = ht[icl][(ty + 1) * 34 + tx + 1];
    // 64 (t,o) dot-product accumulations; Wt loads are wave-uniform -> s_load
    #pragma unroll
    for (int to = 0; to < 64; ++to) {
      const float4 w0 = *(const float4*)(Wt + (size_t)to * C2c + icc);
      const float4 w1 = *(const float4*)(Wt + (size_t)to * C2c + icc + 4);
      float s = accs[to];
      s = fmaf(w0.x, xh[0], s); s = fmaf(w0.y, xh[1], s);
      s = fmaf(w0.z, xh[2], s); s = fmaf(w0.w, xh[3], s);
      s = fmaf(w1.x, xh[4], s); s = fmaf(w1.y, xh[5], s);
      s = fmaf(w1.z, xh[6], s); s = fmaf(w1.w, xh[7], s);
      accs[to] = s;
    }
    // AU 3x3 conv from the same LDS tile
    #pragma unroll
    for (int icl = 0; icl < ICC; ++icl) {
      float n[9];
      #pragma unroll
      for (int k = 0; k < 9; ++k)
        n[k] = ht[icl][(ty + k / 3) * 34 + tx + k % 3];
      const float* wa = W_aue + (size_t)(icc + icl) * 9;
      #pragma unroll
      for (int o = 0; o < 4; ++o) {
        float s = accA[o];
        #pragma unroll
        for (int k = 0; k < 9; ++k)
          s = fmaf(wa[(size_t)o * C2c * 9 + k], n[k], s);  // uniform -> s_load
        accA[o] = s;
      }
    }
  }

  const size_t pixoff = (size_t)py * Ww + px;
  const size_t plane = (size_t)Bsz * 4 * HW;
  #pragma unroll
  for (int o = 0; o < 4; ++o) {
    float bo = b_out[o];
    float sv[Tt];
    float sum = 0.f;
    #pragma unroll
    for (int t = 0; t < Tt; ++t) {
      float v = accs[t * 4 + o] + bo;
      float e = __expf(2.f * v);
      float th = 1.f - 2.f / (e + 1.f);       // tanh(v), exact identity
      sv[t] = th; sum += th;
    }
    float m = sum * (1.f / 16.f);
    float var = 0.f;
    #pragma unroll
    for (int t = 0; t < Tt; ++t) { float d = sv[t] - m; var = fmaf(d, d, var); }
    var *= (1.f / 15.f);                       // ddof=1; lms const over t -> no effect on var
    float lm = lms[((size_t)b * 4 + o) * HW + pixoff];
    float au = accA[o] + b_aue[o];
    au = 1.f / (1.f + __expf(-au));
    size_t oidx = ((size_t)b * 4 + o) * HW + pixoff;
    out[oidx] = au;                 // AU
    out[plane + oidx] = var;        // EU
    out[2 * plane + oidx] = m + lm; // mean
  }
}

extern "C" void kernel_launch(void* const* d_in, const int* in_sizes, int n_in,
                              void* d_out, int out_size, void* d_ws, size_t ws_size,
                              hipStream_t stream) {
  const float* x      = (const float*)d_in[0];
  const float* lms    = (const float*)d_in[1];
  const float* W_conv = (const float*)d_in[2];
  const float* b_conv = (const float*)d_in[3];
  const float* W_out  = (const float*)d_in[4];
  const float* b_out  = (const float*)d_in[5];
  const float* W_aue  = (const float*)d_in[6];
  const float* b_aue  = (const float*)d_in[7];
  const float* masks  = (const float*)d_in[8];
  float* out = (float*)d_out;

  float* Wt = (float*)d_ws;                       // 8192 floats
  float* h  = (float*)d_ws + Tt * 4 * C2c;        // h buffer after Wt
  size_t need_full = (size_t)(Tt * 4 * C2c) * 4 + (size_t)Bsz * C2c * HW * 4;

  wt_kernel<<<dim3(32), dim3(256), 0, stream>>>(W_out, masks, Wt);

  if (ws_size >= need_full) {
    // all 4 batches in one pair of launches (h = 128 MiB in ws)
    conv1_kernel<<<dim3(8, 8, 32), dim3(256), 0, stream>>>(x, W_conv, b_conv, h, 0);
    stage2_kernel<<<dim3(8, 32, 4), dim3(256), 0, stream>>>(h, Wt, b_out, W_aue, b_aue, lms, out, 0);
  } else {
    // per-batch h reuse (needs 33.6 MB of ws); stream order serializes correctly
    for (int b = 0; b < Bsz; ++b) {
      conv1_kernel<<<dim3(8, 8, 8), dim3(256), 0, stream>>>(x, W_conv, b_conv, h, b);
      stage2_kernel<<<dim3(8, 32, 1), dim3(256), 0, stream>>>(h, Wt, b_out, W_aue, b_aue, lms, out, b);
    }
  }
}

// Round 3
// 383.749 us; speedup vs baseline: 3.7224x; 3.7224x over previous
//
#include <hip/hip_runtime.h>

#define Bsz 4
#define Cin 64
#define C2c 128
#define Hh 256
#define Ww 256
#define Tt 16
#define HW (Hh*Ww)
#define ICC 8

typedef __attribute__((ext_vector_type(8))) short bf16x8;
typedef __attribute__((ext_vector_type(4))) float f32x4;

// ws layout (bytes), total ~98.4 MB (known ws >= 134 MB from R1 full-path run):
//   h    (bf16) : 0          .. 67108864   [bi][oc:128][y][x]
//   xT   (bf16) : 67108864   .. +33554432  [bi][y][x][ic:64]
//   Wbf  (bf16) : 100663296  .. +147456    [c:18][nt:8][lane:64][j:8] frag-ordered
//   Wt   (f32)  : 100810752  .. +32768     [t*4+o][c:128]
#define H_OFF   0
#define XT_OFF  67108864
#define WBF_OFF 100663296
#define WT_OFF  100810752

__device__ __forceinline__ unsigned short f2bf(float f) {
  union { float f; unsigned u; } cv; cv.f = f;
  unsigned u = cv.u;
  unsigned r = (u + 0x7fffu + ((u >> 16) & 1u)) >> 16;   // RNE
  return (unsigned short)r;
}
__device__ __forceinline__ float bf2f(unsigned short b) {
  union { unsigned u; float f; } cv; cv.u = ((unsigned)b) << 16;
  return cv.f;
}

// ---------- Wt[t*4+o][c] = W_out[o][c] * masks[t][c] ----------
__global__ void wt_kernel(const float* __restrict__ W_out,
                          const float* __restrict__ masks,
                          float* __restrict__ Wt) {
  int i = blockIdx.x * 256 + threadIdx.x;
  if (i < Tt * 4 * C2c) {
    int to = i >> 7, c = i & 127;
    int t = to >> 2, o = to & 3;
    Wt[i] = W_out[o * C2c + c] * masks[t * C2c + c];
  }
}

// ---------- pack W_conv into MFMA B-operand frag order, bf16 ----------
// B[k][n] for chunk c: k = q*8+j -> ic = (c&1)*32 + q*8 + j, tap = c>>1; n = nt*16 + (lane&15)
__global__ void wpack_kernel(const float* __restrict__ Wc, unsigned short* __restrict__ Wbf) {
  int idx = blockIdx.x * 256 + threadIdx.x;          // 73728 total
  if (idx < 18 * 8 * 64 * 8) {
    int j = idx & 7;
    int lane = (idx >> 3) & 63;
    int nt = (idx >> 9) & 7;
    int c = idx >> 12;
    int q = lane >> 4;
    int tap = c >> 1;
    int ic = (c & 1) * 32 + q * 8 + j;
    int n = nt * 16 + (lane & 15);
    Wbf[idx] = f2bf(Wc[((size_t)n * Cin + ic) * 9 + tap]);
  }
}

// ---------- x [bi][ic][y][x] f32 -> xT [bi][y][x][ic] bf16 ----------
// grid (4 x-slabs of 64, 256 y, 4 bi), block 256
__global__ __launch_bounds__(256) void xt_kernel(const float* __restrict__ x,
                                                 unsigned short* __restrict__ xT) {
  __shared__ unsigned short xs[64][65];
  const int tid = threadIdx.x;
  const int x0 = blockIdx.x * 64, y = blockIdx.y, bi = blockIdx.z;
  const int tx = tid & 63, ti = tid >> 6;
  #pragma unroll
  for (int i = 0; i < 16; ++i) {
    int ic = ti * 16 + i;
    float v = x[(((size_t)bi * Cin + ic) * Hh + y) * Ww + x0 + tx];
    xs[ic][tx] = f2bf(v);
  }
  __syncthreads();
  const int icg = tid & 7, xl = tid >> 3;            // xl 0..31
  #pragma unroll
  for (int rep = 0; rep < 2; ++rep) {
    int xx = xl + 32 * rep;
    unsigned short u[8];
    #pragma unroll
    for (int k = 0; k < 8; ++k) u[k] = xs[icg * 8 + k][xx];
    *(uint4*)(xT + (((size_t)bi * Hh + y) * Ww + (x0 + xx)) * Cin + icg * 8) = *(uint4*)u;
  }
}

// ---------- conv1 via MFMA implicit GEMM ----------
// block 256 = 4 waves; patch 8 rows x 16 cols; N = 128 oc; K = 576 in 18 chunks of 32
// A staged once in LDS (no K-loop barriers); B-frags direct from L2-resident Wbf
__global__ __launch_bounds__(256, 3) void conv1_mfma(
    const unsigned short* __restrict__ xT, const unsigned short* __restrict__ Wbf,
    const float* __restrict__ bc, unsigned short* __restrict__ hout) {
  __shared__ unsigned short At[10 * 18 * 68];        // [ry][rx][ic+pad4] bf16, 24.5 KB
  const int tid = threadIdx.x;
  const int x0 = blockIdx.x * 16, y0 = blockIdx.y * 8, bi = blockIdx.z;

  // stage A: 10*18*8 groups of 8 ic (16 B each)
  for (int g = tid; g < 10 * 18 * 8; g += 256) {
    int icg = g & 7;
    int rx = (g >> 3) % 18;
    int ry = g / (18 * 8);
    int gy = y0 - 1 + ry, gx = x0 - 1 + rx;
    uint2 lo = make_uint2(0, 0), hi = make_uint2(0, 0);
    if ((unsigned)gy < Hh && (unsigned)gx < Ww) {
      uint4 v = *(const uint4*)(xT + (((size_t)bi * Hh + gy) * Ww + gx) * Cin + icg * 8);
      lo.x = v.x; lo.y = v.y; hi.x = v.z; hi.y = v.w;
    }
    int e = (ry * 18 + rx) * 68 + icg * 8;           // e % 4 == 0 -> 8B aligned
    *(uint2*)(&At[e]) = lo;
    *(uint2*)(&At[e + 4]) = hi;
  }
  __syncthreads();

  const int lane = tid & 63, wv = tid >> 6;
  const int mh = wv & 1, nh = wv >> 1;               // wave: 4 m-tiles x 4 n-tiles
  const int m16 = lane & 15, q = lane >> 4;

  f32x4 acc[4][4];
  #pragma unroll
  for (int i = 0; i < 4; ++i)
    #pragma unroll
    for (int j = 0; j < 4; ++j) acc[i][j] = (f32x4){0.f, 0.f, 0.f, 0.f};

  union U8 { uint2 u[2]; bf16x8 v; };

  #pragma unroll
  for (int c = 0; c < 18; ++c) {
    const int tap = c >> 1, ichalf = (c & 1) * 32;
    const int dy = tap / 3, dx = tap % 3;
    // B frags: global, frag-ordered, L2-resident
    bf16x8 bfr[4];
    const unsigned short* wb = Wbf + ((size_t)(c * 8 + nh * 4) * 64 + lane) * 8;
    #pragma unroll
    for (int j = 0; j < 4; ++j)
      bfr[j] = ((const U8*)(wb + j * 512))->v;
    // A frags: LDS, two b64 reads each (2-way banks = free)
    bf16x8 afr[4];
    const int ebase = ((mh * 4 + dy) * 18 + m16 + dx) * 68 + ichalf + q * 8;
    #pragma unroll
    for (int i = 0; i < 4; ++i) {
      U8 t;
      t.u[0] = *(const uint2*)(&At[ebase + i * (18 * 68)]);
      t.u[1] = *(const uint2*)(&At[ebase + i * (18 * 68) + 4]);
      afr[i] = t.v;
    }
    #pragma unroll
    for (int i = 0; i < 4; ++i)
      #pragma unroll
      for (int j = 0; j < 4; ++j)
        acc[i][j] = __builtin_amdgcn_mfma_f32_16x16x32_bf16(afr[i], bfr[j], acc[i][j], 0, 0, 0);
  }

  // epilogue: D layout n = lane&15 (oc), m = q*4 + r (pixel x)
  #pragma unroll
  for (int j = 0; j < 4; ++j) {
    const int oc = (nh * 4 + j) * 16 + m16;
    const float bias = bc[oc];
    #pragma unroll
    for (int i = 0; i < 4; ++i) {
      const int y = y0 + mh * 4 + i;
      unsigned short* hp = hout + ((size_t)(bi * C2c + oc) * Hh + y) * Ww + x0 + q * 4;
      #pragma unroll
      for (int r = 0; r < 4; ++r)
        hp[r] = f2bf(acc[i][j][r] + bias);
    }
  }
}

// ---------- stage2: samples GEMV + stats + AU conv, fused (R1 form, bf16 h) ----------
__global__ void stage2_kernel(
    const unsigned short* __restrict__ h, const float* __restrict__ Wt,
    const float* __restrict__ b_out, const float* __restrict__ W_aue,
    const float* __restrict__ b_aue, const float* __restrict__ lms,
    float* __restrict__ out) {
  __shared__ float ht[ICC][10 * 34];
  const int tid = threadIdx.x;
  const int tx = tid & 31, ty = tid >> 5;
  const int x0 = blockIdx.x * 32, y0 = blockIdx.y * 8;
  const int bi = blockIdx.z;
  const unsigned short* hb = h + (size_t)bi * C2c * HW;
  const int px = x0 + tx, py = y0 + ty;

  float accs[64];
  #pragma unroll
  for (int i = 0; i < 64; ++i) accs[i] = 0.f;
  float accA[4] = {0.f, 0.f, 0.f, 0.f};

  #pragma unroll 1
  for (int icc = 0; icc < C2c; icc += ICC) {
    __syncthreads();
    for (int i = tid; i < ICC * 10 * 34; i += 256) {
      int icl = i / 340; int rem = i % 340;
      int yy = rem / 34, xx = rem % 34;
      int gy = y0 - 1 + yy, gx = x0 - 1 + xx;
      float v = 0.f;
      if ((unsigned)gy < Hh && (unsigned)gx < Ww)
        v = bf2f(hb[(size_t)(icc + icl) * HW + gy * Ww + gx]);
      ht[icl][rem] = v;
    }
    __syncthreads();
    float xh[ICC];
    #pragma unroll
    for (int icl = 0; icl < ICC; ++icl)
      xh[icl] = ht[icl][(ty + 1) * 34 + tx + 1];
    #pragma unroll
    for (int to = 0; to < 64; ++to) {
      const float4 w0 = *(const float4*)(Wt + (size_t)to * C2c + icc);
      const float4 w1 = *(const float4*)(Wt + (size_t)to * C2c + icc + 4);
      float s = accs[to];
      s = fmaf(w0.x, xh[0], s); s = fmaf(w0.y, xh[1], s);
      s = fmaf(w0.z, xh[2], s); s = fmaf(w0.w, xh[3], s);
      s = fmaf(w1.x, xh[4], s); s = fmaf(w1.y, xh[5], s);
      s = fmaf(w1.z, xh[6], s); s = fmaf(w1.w, xh[7], s);
      accs[to] = s;
    }
    #pragma unroll
    for (int icl = 0; icl < ICC; ++icl) {
      float n[9];
      #pragma unroll
      for (int k = 0; k < 9; ++k)
        n[k] = ht[icl][(ty + k / 3) * 34 + tx + k % 3];
      const float* wa = W_aue + (size_t)(icc + icl) * 9;
      #pragma unroll
      for (int o = 0; o < 4; ++o) {
        float s = accA[o];
        #pragma unroll
        for (int k = 0; k < 9; ++k)
          s = fmaf(wa[(size_t)o * C2c * 9 + k], n[k], s);
        accA[o] = s;
      }
    }
  }

  const size_t pixoff = (size_t)py * Ww + px;
  const size_t plane = (size_t)Bsz * 4 * HW;
  #pragma unroll
  for (int o = 0; o < 4; ++o) {
    float bo = b_out[o];
    float sv[Tt];
    float sum = 0.f;
    #pragma unroll
    for (int t = 0; t < Tt; ++t) {
      float v = accs[t * 4 + o] + bo;
      float e = __expf(2.f * v);
      float th = 1.f - 2.f / (e + 1.f);
      sv[t] = th; sum += th;
    }
    float m = sum * (1.f / 16.f);
    float var = 0.f;
    #pragma unroll
    for (int t = 0; t < Tt; ++t) { float d = sv[t] - m; var = fmaf(d, d, var); }
    var *= (1.f / 15.f);
    float lm = lms[((size_t)bi * 4 + o) * HW + pixoff];
    float au = accA[o] + b_aue[o];
    au = 1.f / (1.f + __expf(-au));
    size_t oidx = ((size_t)bi * 4 + o) * HW + pixoff;
    out[oidx] = au;
    out[plane + oidx] = var;
    out[2 * plane + oidx] = m + lm;
  }
}

extern "C" void kernel_launch(void* const* d_in, const int* in_sizes, int n_in,
                              void* d_out, int out_size, void* d_ws, size_t ws_size,
                              hipStream_t stream) {
  const float* x      = (const float*)d_in[0];
  const float* lms    = (const float*)d_in[1];
  const float* W_conv = (const float*)d_in[2];
  const float* b_conv = (const float*)d_in[3];
  const float* W_out  = (const float*)d_in[4];
  const float* b_out  = (const float*)d_in[5];
  const float* W_aue  = (const float*)d_in[6];
  const float* b_aue  = (const float*)d_in[7];
  const float* masks  = (const float*)d_in[8];
  float* out = (float*)d_out;

  char* ws = (char*)d_ws;
  unsigned short* h   = (unsigned short*)(ws + H_OFF);
  unsigned short* xT  = (unsigned short*)(ws + XT_OFF);
  unsigned short* Wbf = (unsigned short*)(ws + WBF_OFF);
  float*          Wt  = (float*)(ws + WT_OFF);

  wt_kernel<<<dim3(32), dim3(256), 0, stream>>>(W_out, masks, Wt);
  wpack_kernel<<<dim3(288), dim3(256), 0, stream>>>(W_conv, Wbf);
  xt_kernel<<<dim3(4, 256, 4), dim3(256), 0, stream>>>(x, xT);
  conv1_mfma<<<dim3(16, 32, 4), dim3(256), 0, stream>>>(xT, Wbf, b_conv, h);
  stage2_kernel<<<dim3(8, 32, 4), dim3(256), 0, stream>>>(h, Wt, b_out, W_aue, b_aue, lms, out);
}

// Round 4
// 355.949 us; speedup vs baseline: 4.0132x; 1.0781x over previous
//
#include <hip/hip_runtime.h>

#define Bsz 4
#define Cin 64
#define C2c 128
#define Hh 256
#define Ww 256
#define Tt 16
#define HW (Hh*Ww)
#define PLANE (Bsz*4*HW)

typedef __attribute__((ext_vector_type(8))) short bf16x8;
typedef __attribute__((ext_vector_type(4))) float f32x4;

// ws layout (bytes), total ~100.9 MB (ws >= 134 MB confirmed in R1):
//   h    (bf16) : 0          .. 67108864   [bi][y][x][oc:128]  PIXEL-MAJOR
//   xT   (bf16) : 67108864   .. +33554432  [bi][y][x][ic:64]
//   Wbf  (bf16) : 100663296  .. +147456    [c:18][octile:8][lane:64][j:8] frag-ordered
//   Wtb  (bf16) : 100810752  .. +16384     [to:64][c:128] row-major
//   Aub  (bf16) : 100827136  .. +36864     [m:16][k:1152] (rows 4..15 zero)
#define H_OFF   0
#define XT_OFF  67108864
#define WBF_OFF 100663296
#define WTB_OFF 100810752
#define AUB_OFF 100827136

__device__ __forceinline__ unsigned short f2bf(float f) {
  union { float f; unsigned u; } cv; cv.f = f;
  unsigned u = cv.u;
  unsigned r = (u + 0x7fffu + ((u >> 16) & 1u)) >> 16;   // RNE
  return (unsigned short)r;
}

union U8 { uint2 u2[2]; uint4 u4; bf16x8 v; };

// ---------- Wtb[to][c] = bf16(W_out[o][c] * masks[t][c]), to = t*4+o ----------
__global__ void wtb_kernel(const float* __restrict__ W_out,
                           const float* __restrict__ masks,
                           unsigned short* __restrict__ Wtb) {
  int i = blockIdx.x * 256 + threadIdx.x;
  if (i < 64 * C2c) {
    int to = i >> 7, c = i & 127;
    int t = to >> 2, o = to & 3;
    Wtb[i] = f2bf(W_out[o * C2c + c] * masks[t * C2c + c]);
  }
}

// ---------- pack W_conv into MFMA frag order (A-role in conv1) ----------
// frag elem (c, octile, lane, j): oc = octile*16 + (lane&15), k = (lane>>4)*8+j
//   -> ic = (c&1)*32 + (lane>>4)*8 + j, tap = c>>1
__global__ void wpack_kernel(const float* __restrict__ Wc, unsigned short* __restrict__ Wbf) {
  int idx = blockIdx.x * 256 + threadIdx.x;          // 73728 total
  if (idx < 18 * 8 * 64 * 8) {
    int j = idx & 7;
    int lane = (idx >> 3) & 63;
    int nt = (idx >> 9) & 7;
    int c = idx >> 12;
    int q = lane >> 4;
    int tap = c >> 1;
    int ic = (c & 1) * 32 + q * 8 + j;
    int n = nt * 16 + (lane & 15);
    Wbf[idx] = f2bf(Wc[((size_t)n * Cin + ic) * 9 + tap]);
  }
}

// ---------- Aub[m][k]: m=o (rows>=4 zero), k = tap*128 + c ----------
__global__ void aupack_kernel(const float* __restrict__ W_aue, unsigned short* __restrict__ Aub) {
  int i = blockIdx.x * 256 + threadIdx.x;            // 18432 total
  if (i < 16 * 1152) {
    int m = i / 1152, k = i % 1152;
    int tap = k >> 7, c = k & 127;
    float v = (m < 4) ? W_aue[((size_t)m * C2c + c) * 9 + tap] : 0.f;
    Aub[i] = f2bf(v);
  }
}

// ---------- x [bi][ic][y][x] f32 -> xT [bi][y][x][ic] bf16 ----------
__global__ __launch_bounds__(256) void xt_kernel(const float* __restrict__ x,
                                                 unsigned short* __restrict__ xT) {
  __shared__ unsigned short xs[64][65];
  const int tid = threadIdx.x;
  const int x0 = blockIdx.x * 64, y = blockIdx.y, bi = blockIdx.z;
  const int tx = tid & 63, ti = tid >> 6;
  #pragma unroll
  for (int i = 0; i < 16; ++i) {
    int ic = ti * 16 + i;
    float v = x[(((size_t)bi * Cin + ic) * Hh + y) * Ww + x0 + tx];
    xs[ic][tx] = f2bf(v);
  }
  __syncthreads();
  const int icg = tid & 7, xl = tid >> 3;
  #pragma unroll
  for (int rep = 0; rep < 2; ++rep) {
    int xx = xl + 32 * rep;
    unsigned short u[8];
    #pragma unroll
    for (int k = 0; k < 8; ++k) u[k] = xs[icg * 8 + k][xx];
    *(uint4*)(xT + (((size_t)bi * Hh + y) * Ww + (x0 + xx)) * Cin + icg * 8) = *(uint4*)u;
  }
}

// ---------- conv1 via MFMA implicit GEMM: A=weights(m=oc), B=x-patch(n=px) ----------
// D: n=px-x=lane&15, m=oc=q*4+r -> pixel-major ushort4 h writes
__global__ __launch_bounds__(256, 3) void conv1_mfma(
    const unsigned short* __restrict__ xT, const unsigned short* __restrict__ Wbf,
    const float* __restrict__ bc, unsigned short* __restrict__ hout) {
  __shared__ unsigned short At[10 * 18 * 68];        // [ry][rx][ic+pad4], 24.5 KB
  const int tid = threadIdx.x;
  const int x0 = blockIdx.x * 16, y0 = blockIdx.y * 8, bi = blockIdx.z;

  for (int g = tid; g < 10 * 18 * 8; g += 256) {
    int icg = g & 7;
    int rx = (g >> 3) % 18;
    int ry = g / (18 * 8);
    int gy = y0 - 1 + ry, gx = x0 - 1 + rx;
    uint2 lo = make_uint2(0, 0), hi = make_uint2(0, 0);
    if ((unsigned)gy < Hh && (unsigned)gx < Ww) {
      uint4 v = *(const uint4*)(xT + (((size_t)bi * Hh + gy) * Ww + gx) * Cin + icg * 8);
      lo.x = v.x; lo.y = v.y; hi.x = v.z; hi.y = v.w;
    }
    int e = (ry * 18 + rx) * 68 + icg * 8;
    *(uint2*)(&At[e]) = lo;
    *(uint2*)(&At[e + 4]) = hi;
  }
  __syncthreads();

  const int lane = tid & 63, wv = tid >> 6;
  const int wo = wv & 1, wy = wv >> 1;               // oc-half, y-half
  const int n16 = lane & 15, q = lane >> 4;

  f32x4 acc[4][4];                                    // [i=oc-tile][j=y-row]
  #pragma unroll
  for (int i = 0; i < 4; ++i)
    #pragma unroll
    for (int j = 0; j < 4; ++j) acc[i][j] = (f32x4){0.f, 0.f, 0.f, 0.f};

  #pragma unroll
  for (int c = 0; c < 18; ++c) {
    const int tap = c >> 1, ichalf = (c & 1) * 32;
    const int dy = tap / 3, dx = tap % 3;
    bf16x8 wfr[4];                                    // A: weights (global, L2-resident)
    const unsigned short* wb = Wbf + ((size_t)(c * 8 + wo * 4) * 64 + lane) * 8;
    #pragma unroll
    for (int i = 0; i < 4; ++i)
      wfr[i] = ((const U8*)(wb + i * 512))->v;
    bf16x8 xfr[4];                                    // B: x-patch (LDS)
    const int ebase = ((wy * 4 + dy) * 18 + n16 + dx) * 68 + ichalf + q * 8;
    #pragma unroll
    for (int j = 0; j < 4; ++j) {
      U8 t;
      t.u2[0] = *(const uint2*)(&At[ebase + j * (18 * 68)]);
      t.u2[1] = *(const uint2*)(&At[ebase + j * (18 * 68) + 4]);
      xfr[j] = t.v;
    }
    #pragma unroll
    for (int i = 0; i < 4; ++i)
      #pragma unroll
      for (int j = 0; j < 4; ++j)
        acc[i][j] = __builtin_amdgcn_mfma_f32_16x16x32_bf16(wfr[i], xfr[j], acc[i][j], 0, 0, 0);
  }

  #pragma unroll
  for (int i = 0; i < 4; ++i) {
    const int ocb = (wo * 4 + i) * 16 + q * 4;
    const float4 b4 = *(const float4*)(bc + ocb);
    #pragma unroll
    for (int j = 0; j < 4; ++j) {
      const int y = y0 + wy * 4 + j;
      ushort4 o4;
      o4.x = f2bf(acc[i][j][0] + b4.x);
      o4.y = f2bf(acc[i][j][1] + b4.y);
      o4.z = f2bf(acc[i][j][2] + b4.z);
      o4.w = f2bf(acc[i][j][3] + b4.w);
      *(ushort4*)(hout + (((size_t)bi * Hh + y) * Ww + x0 + n16) * C2c + ocb) = o4;
    }
  }
}

// ---------- stage2: MFMA GEMV (C[to][px]) + MFMA AU conv + shuffle stats ----------
// block 256 = 4 waves, each wave = 16 px of one row; NO LDS, NO barriers
__global__ __launch_bounds__(256) void stage2_kernel(
    const unsigned short* __restrict__ h, const unsigned short* __restrict__ Wtb,
    const unsigned short* __restrict__ Aub, const float* __restrict__ b_out,
    const float* __restrict__ b_aue, const float* __restrict__ lms,
    float* __restrict__ out) {
  const int tid = threadIdx.x;
  const int lane = tid & 63, wv = tid >> 6;
  const int n16 = lane & 15, q = lane >> 4;
  const int y = blockIdx.y, bi = blockIdx.z;
  const int x0 = blockIdx.x * 64 + wv * 16;
  const int px = x0 + n16;
  const unsigned short* hb = h + (size_t)bi * HW * C2c;   // [y][x][oc]

  // ---- GEMV: D[m=to][n=px], A=Wtb, B=h center pixel ----
  f32x4 acc[4];
  #pragma unroll
  for (int mt = 0; mt < 4; ++mt) acc[mt] = (f32x4){0.f, 0.f, 0.f, 0.f};
  const unsigned short* hc = hb + ((size_t)y * Ww + px) * C2c;
  #pragma unroll
  for (int kc = 0; kc < 4; ++kc) {
    bf16x8 bfr = ((const U8*)(hc + kc * 32 + q * 8))->v;
    #pragma unroll
    for (int mt = 0; mt < 4; ++mt) {
      bf16x8 afr = ((const U8*)(Wtb + (size_t)(mt * 16 + n16) * C2c + kc * 32 + q * 8))->v;
      acc[mt] = __builtin_amdgcn_mfma_f32_16x16x32_bf16(afr, bfr, acc[mt], 0, 0, 0);
    }
  }

  // ---- AU: D[m=o][n=px], A=Aub (rows>=4 zero), B=h 3x3 neighborhood ----
  f32x4 accA = (f32x4){0.f, 0.f, 0.f, 0.f};
  #pragma unroll
  for (int cc = 0; cc < 36; ++cc) {
    const int tap = cc >> 2;
    const int gy = y + tap / 3 - 1;
    const int gx = px + tap % 3 - 1;
    U8 b; b.u4 = make_uint4(0, 0, 0, 0);
    if ((unsigned)gy < Hh && (unsigned)gx < Ww)
      b.u4 = *(const uint4*)(hb + ((size_t)gy * Ww + gx) * C2c + (cc & 3) * 32 + q * 8);
    bf16x8 afr = ((const U8*)(Aub + (size_t)n16 * 1152 + cc * 32 + q * 8))->v;
    accA = __builtin_amdgcn_mfma_f32_16x16x32_bf16(afr, b.v, accA, 0, 0, 0);
  }

  // ---- stats: lane holds to = mt*16 + q*4 + r  ->  t = 4*mt+q, o = r ----
  const float b0 = b_out[0], b1 = b_out[1], b2 = b_out[2], b3 = b_out[3];
  float th[4][4];
  #pragma unroll
  for (int mt = 0; mt < 4; ++mt) {
    #pragma unroll
    for (int r = 0; r < 4; ++r) {
      float bo = (r == 0) ? b0 : (r == 1) ? b1 : (r == 2) ? b2 : b3;
      float v = acc[mt][r] + bo;
      float e = __expf(2.f * v);
      th[mt][r] = 1.f - 2.f / (e + 1.f);              // tanh(v)
    }
  }
  float mean_r[4], eu_r[4];
  #pragma unroll
  for (int r = 0; r < 4; ++r) {
    float s = th[0][r] + th[1][r] + th[2][r] + th[3][r];
    s += __shfl_xor(s, 16);
    s += __shfl_xor(s, 32);                           // sum over all 16 t
    float m = s * (1.f / 16.f);
    float d0 = th[0][r] - m, d1 = th[1][r] - m, d2 = th[2][r] - m, d3 = th[3][r] - m;
    float vs = d0 * d0 + d1 * d1 + d2 * d2 + d3 * d3;
    vs += __shfl_xor(vs, 16);
    vs += __shfl_xor(vs, 32);
    mean_r[r] = m;
    eu_r[r] = vs * (1.f / 15.f);                      // ddof=1
  }
  // AU preacts live in lanes q'=0 (lane = n16), register r = o; broadcast
  float au_r[4];
  #pragma unroll
  for (int r = 0; r < 4; ++r) au_r[r] = __shfl(accA[r], n16);

  // lane writes o = q
  float m_q  = (q == 0) ? mean_r[0] : (q == 1) ? mean_r[1] : (q == 2) ? mean_r[2] : mean_r[3];
  float eu_q = (q == 0) ? eu_r[0]   : (q == 1) ? eu_r[1]   : (q == 2) ? eu_r[2]   : eu_r[3];
  float au_q = (q == 0) ? au_r[0]   : (q == 1) ? au_r[1]   : (q == 2) ? au_r[2]   : au_r[3];
  au_q = 1.f / (1.f + __expf(-(au_q + b_aue[q])));
  size_t oidx = ((size_t)(bi * 4 + q)) * HW + (size_t)y * Ww + px;
  float lm = lms[oidx];
  out[oidx] = au_q;                                   // AU
  out[PLANE + oidx] = eu_q;                           // EU
  out[2 * (size_t)PLANE + oidx] = m_q + lm;           // mean
}

extern "C" void kernel_launch(void* const* d_in, const int* in_sizes, int n_in,
                              void* d_out, int out_size, void* d_ws, size_t ws_size,
                              hipStream_t stream) {
  const float* x      = (const float*)d_in[0];
  const float* lms    = (const float*)d_in[1];
  const float* W_conv = (const float*)d_in[2];
  const float* b_conv = (const float*)d_in[3];
  const float* W_out  = (const float*)d_in[4];
  const float* b_out  = (const float*)d_in[5];
  const float* W_aue  = (const float*)d_in[6];
  const float* b_aue  = (const float*)d_in[7];
  const float* masks  = (const float*)d_in[8];
  float* out = (float*)d_out;

  char* ws = (char*)d_ws;
  unsigned short* h   = (unsigned short*)(ws + H_OFF);
  unsigned short* xT  = (unsigned short*)(ws + XT_OFF);
  unsigned short* Wbf = (unsigned short*)(ws + WBF_OFF);
  unsigned short* Wtb = (unsigned short*)(ws + WTB_OFF);
  unsigned short* Aub = (unsigned short*)(ws + AUB_OFF);

  wtb_kernel<<<dim3(32), dim3(256), 0, stream>>>(W_out, masks, Wtb);
  wpack_kernel<<<dim3(288), dim3(256), 0, stream>>>(W_conv, Wbf);
  aupack_kernel<<<dim3(72), dim3(256), 0, stream>>>(W_aue, Aub);
  xt_kernel<<<dim3(4, 256, 4), dim3(256), 0, stream>>>(x, xT);
  conv1_mfma<<<dim3(16, 32, 4), dim3(256), 0, stream>>>(xT, Wbf, b_conv, h);
  stage2_kernel<<<dim3(4, 256, 4), dim3(256), 0, stream>>>(h, Wtb, Aub, b_out, b_aue, lms, out);
}

// Round 5
// 265.896 us; speedup vs baseline: 5.3724x; 1.3387x over previous
//
#include <hip/hip_runtime.h>

#define Bsz 4
#define Cin 64
#define C2c 128
#define Hh 256
#define Ww 256
#define Tt 16
#define HW (Hh*Ww)
#define PLANE (Bsz*4*HW)

typedef __attribute__((ext_vector_type(8))) short bf16x8;
typedef __attribute__((ext_vector_type(4))) float f32x4;

// ws layout (bytes), total ~100.9 MB:
//   h    (bf16) : 0          .. 67108864   [bi][y][x][oc:128]  PIXEL-MAJOR
//   xT   (bf16) : 67108864   .. +33554432  [bi][y][x][ic:64]
//   Wbf  (bf16) : 100663296  .. +147456    [c:18][octile:8][lane:64][j:8] frag-ordered
//   Wtb  (bf16) : 100810752  .. +16384     [to:64][c:128] row-major
//   Aub  (bf16) : 100827136  .. +36864     [m:16][k:1152] (rows 4..15 zero)
#define H_OFF   0
#define XT_OFF  67108864
#define WBF_OFF 100663296
#define WTB_OFF 100810752
#define AUB_OFF 100827136

__device__ __forceinline__ unsigned short f2bf(float f) {
  union { float f; unsigned u; } cv; cv.f = f;
  unsigned u = cv.u;
  unsigned r = (u + 0x7fffu + ((u >> 16) & 1u)) >> 16;   // RNE
  return (unsigned short)r;
}

union U8 { uint2 u2[2]; uint4 u4; bf16x8 v; };

// ---------- Wtb[to][c] = bf16(W_out[o][c] * masks[t][c]), to = t*4+o ----------
__global__ void wtb_kernel(const float* __restrict__ W_out,
                           const float* __restrict__ masks,
                           unsigned short* __restrict__ Wtb) {
  int i = blockIdx.x * 256 + threadIdx.x;
  if (i < 64 * C2c) {
    int to = i >> 7, c = i & 127;
    int t = to >> 2, o = to & 3;
    Wtb[i] = f2bf(W_out[o * C2c + c] * masks[t * C2c + c]);
  }
}

// ---------- pack W_conv into MFMA frag order (A-role in conv1) ----------
__global__ void wpack_kernel(const float* __restrict__ Wc, unsigned short* __restrict__ Wbf) {
  int idx = blockIdx.x * 256 + threadIdx.x;          // 73728 total
  if (idx < 18 * 8 * 64 * 8) {
    int j = idx & 7;
    int lane = (idx >> 3) & 63;
    int nt = (idx >> 9) & 7;
    int c = idx >> 12;
    int q = lane >> 4;
    int tap = c >> 1;
    int ic = (c & 1) * 32 + q * 8 + j;
    int n = nt * 16 + (lane & 15);
    Wbf[idx] = f2bf(Wc[((size_t)n * Cin + ic) * 9 + tap]);
  }
}

// ---------- Aub[m][k]: m=o (rows>=4 zero), k = tap*128 + c ----------
__global__ void aupack_kernel(const float* __restrict__ W_aue, unsigned short* __restrict__ Aub) {
  int i = blockIdx.x * 256 + threadIdx.x;            // 18432 total
  if (i < 16 * 1152) {
    int m = i / 1152, k = i % 1152;
    int tap = k >> 7, c = k & 127;
    float v = (m < 4) ? W_aue[((size_t)m * C2c + c) * 9 + tap] : 0.f;
    Aub[i] = f2bf(v);
  }
}

// ---------- x [bi][ic][y][x] f32 -> xT [bi][y][x][ic] bf16 ----------
__global__ __launch_bounds__(256) void xt_kernel(const float* __restrict__ x,
                                                 unsigned short* __restrict__ xT) {
  __shared__ unsigned short xs[64][65];
  const int tid = threadIdx.x;
  const int x0 = blockIdx.x * 64, y = blockIdx.y, bi = blockIdx.z;
  const int tx = tid & 63, ti = tid >> 6;
  #pragma unroll
  for (int i = 0; i < 16; ++i) {
    int ic = ti * 16 + i;
    float v = x[(((size_t)bi * Cin + ic) * Hh + y) * Ww + x0 + tx];
    xs[ic][tx] = f2bf(v);
  }
  __syncthreads();
  const int icg = tid & 7, xl = tid >> 3;
  #pragma unroll
  for (int rep = 0; rep < 2; ++rep) {
    int xx = xl + 32 * rep;
    unsigned short u[8];
    #pragma unroll
    for (int k = 0; k < 8; ++k) u[k] = xs[icg * 8 + k][xx];
    *(uint4*)(xT + (((size_t)bi * Hh + y) * Ww + (x0 + xx)) * Cin + icg * 8) = *(uint4*)u;
  }
}

// ---------- conv1 via MFMA implicit GEMM: A=weights(m=oc), B=x-patch(n=px) ----------
__global__ __launch_bounds__(256, 3) void conv1_mfma(
    const unsigned short* __restrict__ xT, const unsigned short* __restrict__ Wbf,
    const float* __restrict__ bc, unsigned short* __restrict__ hout) {
  __shared__ unsigned short At[10 * 18 * 68];        // [ry][rx][ic+pad4], 24.5 KB
  const int tid = threadIdx.x;
  const int x0 = blockIdx.x * 16, y0 = blockIdx.y * 8, bi = blockIdx.z;

  for (int g = tid; g < 10 * 18 * 8; g += 256) {
    int icg = g & 7;
    int rx = (g >> 3) % 18;
    int ry = g / (18 * 8);
    int gy = y0 - 1 + ry, gx = x0 - 1 + rx;
    uint2 lo = make_uint2(0, 0), hi = make_uint2(0, 0);
    if ((unsigned)gy < Hh && (unsigned)gx < Ww) {
      uint4 v = *(const uint4*)(xT + (((size_t)bi * Hh + gy) * Ww + gx) * Cin + icg * 8);
      lo.x = v.x; lo.y = v.y; hi.x = v.z; hi.y = v.w;
    }
    int e = (ry * 18 + rx) * 68 + icg * 8;
    *(uint2*)(&At[e]) = lo;
    *(uint2*)(&At[e + 4]) = hi;
  }
  __syncthreads();

  const int lane = tid & 63, wv = tid >> 6;
  const int wo = wv & 1, wy = wv >> 1;
  const int n16 = lane & 15, q = lane >> 4;

  f32x4 acc[4][4];
  #pragma unroll
  for (int i = 0; i < 4; ++i)
    #pragma unroll
    for (int j = 0; j < 4; ++j) acc[i][j] = (f32x4){0.f, 0.f, 0.f, 0.f};

  #pragma unroll
  for (int c = 0; c < 18; ++c) {
    const int tap = c >> 1, ichalf = (c & 1) * 32;
    const int dy = tap / 3, dx = tap % 3;
    bf16x8 wfr[4];
    const unsigned short* wb = Wbf + ((size_t)(c * 8 + wo * 4) * 64 + lane) * 8;
    #pragma unroll
    for (int i = 0; i < 4; ++i)
      wfr[i] = ((const U8*)(wb + i * 512))->v;
    bf16x8 xfr[4];
    const int ebase = ((wy * 4 + dy) * 18 + n16 + dx) * 68 + ichalf + q * 8;
    #pragma unroll
    for (int j = 0; j < 4; ++j) {
      U8 t;
      t.u2[0] = *(const uint2*)(&At[ebase + j * (18 * 68)]);
      t.u2[1] = *(const uint2*)(&At[ebase + j * (18 * 68) + 4]);
      xfr[j] = t.v;
    }
    #pragma unroll
    for (int i = 0; i < 4; ++i)
      #pragma unroll
      for (int j = 0; j < 4; ++j)
        acc[i][j] = __builtin_amdgcn_mfma_f32_16x16x32_bf16(wfr[i], xfr[j], acc[i][j], 0, 0, 0);
  }

  #pragma unroll
  for (int i = 0; i < 4; ++i) {
    const int ocb = (wo * 4 + i) * 16 + q * 4;
    const float4 b4 = *(const float4*)(bc + ocb);
    #pragma unroll
    for (int j = 0; j < 4; ++j) {
      const int y = y0 + wy * 4 + j;
      ushort4 o4;
      o4.x = f2bf(acc[i][j][0] + b4.x);
      o4.y = f2bf(acc[i][j][1] + b4.y);
      o4.z = f2bf(acc[i][j][2] + b4.z);
      o4.w = f2bf(acc[i][j][3] + b4.w);
      *(ushort4*)(hout + (((size_t)bi * Hh + y) * Ww + x0 + n16) * C2c + ocb) = o4;
    }
  }
}

// ---------- stage2: LDS-tiled MFMA GEMV + MFMA AU conv + shuffle stats ----------
// block 256 = 4 waves; tile 16 px x 8 rows; halo tile 18 x 10 staged once in LDS.
// Pixel record padded to 132 shorts (264 B): 16-px-stride b64 reads land 4 words/bank
// (the wave64-b64 floor) = conflict-free.
#define S2P 132
__global__ __launch_bounds__(256, 3) void stage2_mfma(
    const unsigned short* __restrict__ h, const unsigned short* __restrict__ Wtb,
    const unsigned short* __restrict__ Aub, const float* __restrict__ b_out,
    const float* __restrict__ b_aue, const float* __restrict__ lms,
    float* __restrict__ out) {
  __shared__ unsigned short ht[10 * 18 * S2P];       // 47.5 KB
  const int tid = threadIdx.x;
  const int x0 = blockIdx.x * 16, y0 = blockIdx.y * 8, bi = blockIdx.z;
  const unsigned short* hb = h + (size_t)bi * HW * C2c;

  // stage: 10 rows x 18 px x 16 parts of 16 B, coalesced global reads
  for (int g = tid; g < 10 * 18 * 16; g += 256) {
    int part = g & 15;
    int rx = (g >> 4) % 18;
    int ry = g / (18 * 16);
    int gy = y0 - 1 + ry, gx = x0 - 1 + rx;
    uint2 lo = make_uint2(0, 0), hi = make_uint2(0, 0);
    if ((unsigned)gy < Hh && (unsigned)gx < Ww) {
      uint4 v = *(const uint4*)(hb + ((size_t)gy * Ww + gx) * C2c + part * 8);
      lo.x = v.x; lo.y = v.y; hi.x = v.z; hi.y = v.w;
    }
    int e = (ry * 18 + rx) * S2P + part * 8;
    *(uint2*)(&ht[e]) = lo;
    *(uint2*)(&ht[e + 4]) = hi;
  }
  __syncthreads();

  const int lane = tid & 63, wv = tid >> 6;
  const int n16 = lane & 15, q = lane >> 4;

  f32x4 accG[2][4];                                  // [nt=row][mt=to-tile]
  f32x4 accA[2];
  #pragma unroll
  for (int nt = 0; nt < 2; ++nt) {
    accA[nt] = (f32x4){0.f, 0.f, 0.f, 0.f};
    #pragma unroll
    for (int mt = 0; mt < 4; ++mt) accG[nt][mt] = (f32x4){0.f, 0.f, 0.f, 0.f};
  }

  // ---- GEMV: D[m=to][n=px], A=Wtb rows (global, L2), B=center px (LDS) ----
  #pragma unroll
  for (int kc = 0; kc < 4; ++kc) {
    bf16x8 afr[4];
    #pragma unroll
    for (int mt = 0; mt < 4; ++mt)
      afr[mt] = ((const U8*)(Wtb + (size_t)(mt * 16 + n16) * C2c + kc * 32 + q * 8))->v;
    #pragma unroll
    for (int nt = 0; nt < 2; ++nt) {
      int e = ((wv * 2 + nt + 1) * 18 + n16 + 1) * S2P + kc * 32 + q * 8;
      U8 b;
      b.u2[0] = *(const uint2*)(&ht[e]);
      b.u2[1] = *(const uint2*)(&ht[e + 4]);
      #pragma unroll
      for (int mt = 0; mt < 4; ++mt)
        accG[nt][mt] = __builtin_amdgcn_mfma_f32_16x16x32_bf16(afr[mt], b.v, accG[nt][mt], 0, 0, 0);
    }
  }

  // ---- AU: D[m=o][n=px], A=Aub rows (global, L2), B=3x3 neighborhood (LDS) ----
  #pragma unroll
  for (int kc = 0; kc < 36; ++kc) {
    const int tap = kc >> 2, co = (kc & 3) * 32;
    const int dy = tap / 3, dx = tap % 3;
    bf16x8 afr = ((const U8*)(Aub + (size_t)n16 * 1152 + kc * 32 + q * 8))->v;
    #pragma unroll
    for (int nt = 0; nt < 2; ++nt) {
      int e = ((wv * 2 + nt + dy) * 18 + n16 + dx) * S2P + co + q * 8;
      U8 b;
      b.u2[0] = *(const uint2*)(&ht[e]);
      b.u2[1] = *(const uint2*)(&ht[e + 4]);
      accA[nt] = __builtin_amdgcn_mfma_f32_16x16x32_bf16(afr, b.v, accA[nt], 0, 0, 0);
    }
  }

  // ---- stats + outputs per row; lane holds to = mt*16 + q*4 + r -> t=4mt+q, o=r ----
  const float b0 = b_out[0], b1 = b_out[1], b2 = b_out[2], b3 = b_out[3];
  const float ba = b_aue[q];
  const int px = x0 + n16;
  #pragma unroll
  for (int nt = 0; nt < 2; ++nt) {
    const int y = y0 + wv * 2 + nt;
    float th[4][4];
    #pragma unroll
    for (int mt = 0; mt < 4; ++mt) {
      #pragma unroll
      for (int r = 0; r < 4; ++r) {
        float bo = (r == 0) ? b0 : (r == 1) ? b1 : (r == 2) ? b2 : b3;
        float v = accG[nt][mt][r] + bo;
        float e = __expf(2.f * v);
        th[mt][r] = 1.f - 2.f / (e + 1.f);            // tanh(v)
      }
    }
    float mean_r[4], eu_r[4];
    #pragma unroll
    for (int r = 0; r < 4; ++r) {
      float s = th[0][r] + th[1][r] + th[2][r] + th[3][r];
      s += __shfl_xor(s, 16);
      s += __shfl_xor(s, 32);
      float m = s * (1.f / 16.f);
      float d0 = th[0][r] - m, d1 = th[1][r] - m, d2 = th[2][r] - m, d3 = th[3][r] - m;
      float vs = d0 * d0 + d1 * d1 + d2 * d2 + d3 * d3;
      vs += __shfl_xor(vs, 16);
      vs += __shfl_xor(vs, 32);
      mean_r[r] = m;
      eu_r[r] = vs * (1.f / 15.f);
    }
    float au_r[4];
    #pragma unroll
    for (int r = 0; r < 4; ++r) au_r[r] = __shfl(accA[nt][r], n16);  // q=0 lanes hold o=r

    float m_q  = (q == 0) ? mean_r[0] : (q == 1) ? mean_r[1] : (q == 2) ? mean_r[2] : mean_r[3];
    float eu_q = (q == 0) ? eu_r[0]   : (q == 1) ? eu_r[1]   : (q == 2) ? eu_r[2]   : eu_r[3];
    float au_q = (q == 0) ? au_r[0]   : (q == 1) ? au_r[1]   : (q == 2) ? au_r[2]   : au_r[3];
    au_q = 1.f / (1.f + __expf(-(au_q + ba)));
    size_t oidx = ((size_t)(bi * 4 + q)) * HW + (size_t)y * Ww + px;
    float lm = lms[oidx];
    out[oidx] = au_q;
    out[PLANE + oidx] = eu_q;
    out[2 * (size_t)PLANE + oidx] = m_q + lm;
  }
}

extern "C" void kernel_launch(void* const* d_in, const int* in_sizes, int n_in,
                              void* d_out, int out_size, void* d_ws, size_t ws_size,
                              hipStream_t stream) {
  const float* x      = (const float*)d_in[0];
  const float* lms    = (const float*)d_in[1];
  const float* W_conv = (const float*)d_in[2];
  const float* b_conv = (const float*)d_in[3];
  const float* W_out  = (const float*)d_in[4];
  const float* b_out  = (const float*)d_in[5];
  const float* W_aue  = (const float*)d_in[6];
  const float* b_aue  = (const float*)d_in[7];
  const float* masks  = (const float*)d_in[8];
  float* out = (float*)d_out;

  char* ws = (char*)d_ws;
  unsigned short* h   = (unsigned short*)(ws + H_OFF);
  unsigned short* xT  = (unsigned short*)(ws + XT_OFF);
  unsigned short* Wbf = (unsigned short*)(ws + WBF_OFF);
  unsigned short* Wtb = (unsigned short*)(ws + WTB_OFF);
  unsigned short* Aub = (unsigned short*)(ws + AUB_OFF);

  wtb_kernel<<<dim3(32), dim3(256), 0, stream>>>(W_out, masks, Wtb);
  wpack_kernel<<<dim3(288), dim3(256), 0, stream>>>(W_conv, Wbf);
  aupack_kernel<<<dim3(72), dim3(256), 0, stream>>>(W_aue, Aub);
  xt_kernel<<<dim3(4, 256, 4), dim3(256), 0, stream>>>(x, xT);
  conv1_mfma<<<dim3(16, 32, 4), dim3(256), 0, stream>>>(xT, Wbf, b_conv, h);
  stage2_mfma<<<dim3(16, 32, 4), dim3(256), 0, stream>>>(h, Wtb, Aub, b_out, b_aue, lms, out);
}

// Round 7
// 223.739 us; speedup vs baseline: 6.3846x; 1.1884x over previous
//
#include <hip/hip_runtime.h>

#define Bsz 4
#define Cin 64
#define C2c 128
#define Hh 256
#define Ww 256
#define Tt 16
#define HW (Hh*Ww)
#define PLANE (Bsz*4*HW)

typedef __attribute__((ext_vector_type(8))) short bf16x8;
typedef __attribute__((ext_vector_type(4))) float f32x4;

// ws layout (bytes): xT 33.5 MB + packed weights (~35 MB total; h eliminated)
#define XT_OFF  0
#define WBF_OFF 33554432
#define WTB_OFF 33701888
#define AUB_OFF 33718272

// LDS record strides (shorts). XP=76, HP=132 (8B-aligned b64 records).
#define XP 76
#define HP 132

__device__ __forceinline__ unsigned short f2bf(float f) {
  union { float f; unsigned u; } cv; cv.f = f;
  unsigned u = cv.u;
  unsigned r = (u + 0x7fffu + ((u >> 16) & 1u)) >> 16;   // RNE
  return (unsigned short)r;
}

union U8 { uint2 u2[2]; uint4 u4; bf16x8 v; };

// ---------- prep: Wtb + Wbf + Aub in one launch ----------
__global__ void prep_kernel(const float* __restrict__ W_out, const float* __restrict__ masks,
                            const float* __restrict__ Wc, const float* __restrict__ W_aue,
                            unsigned short* __restrict__ Wtb, unsigned short* __restrict__ Wbf,
                            unsigned short* __restrict__ Aub) {
  int i = blockIdx.x * 256 + threadIdx.x;
  if (i < 8192) {                                   // Wtb[to][c]
    int to = i >> 7, c = i & 127;
    int t = to >> 2, o = to & 3;
    Wtb[i] = f2bf(W_out[o * C2c + c] * masks[t * C2c + c]);
  } else if (i < 8192 + 73728) {                    // Wbf frag-ordered
    int idx = i - 8192;
    int j = idx & 7;
    int lane = (idx >> 3) & 63;
    int nt = (idx >> 9) & 7;
    int c = idx >> 12;
    int q = lane >> 4;
    int tap = c >> 1;
    int ic = (c & 1) * 32 + q * 8 + j;
    int n = nt * 16 + (lane & 15);
    Wbf[idx] = f2bf(Wc[((size_t)n * Cin + ic) * 9 + tap]);
  } else if (i < 8192 + 73728 + 18432) {            // Aub[m][k], rows>=4 zero
    int idx = i - 8192 - 73728;
    int m = idx / 1152, k = idx % 1152;
    int tap = k >> 7, c = k & 127;
    float v = (m < 4) ? W_aue[((size_t)m * C2c + c) * 9 + tap] : 0.f;
    Aub[idx] = f2bf(v);
  }
}

// ---------- x [bi][ic][y][x] f32 -> xT [bi][y][x][ic] bf16 ----------
__global__ __launch_bounds__(256) void xt_kernel(const float* __restrict__ x,
                                                 unsigned short* __restrict__ xT) {
  __shared__ unsigned short xs[64][65];
  const int tid = threadIdx.x;
  const int x0 = blockIdx.x * 64, y = blockIdx.y, bi = blockIdx.z;
  const int tx = tid & 63, ti = tid >> 6;
  #pragma unroll
  for (int i = 0; i < 16; ++i) {
    int ic = ti * 16 + i;
    float v = x[(((size_t)bi * Cin + ic) * Hh + y) * Ww + x0 + tx];
    xs[ic][tx] = f2bf(v);
  }
  __syncthreads();
  const int icg = tid & 7, xl = tid >> 3;
  #pragma unroll
  for (int rep = 0; rep < 2; ++rep) {
    int xx = xl + 32 * rep;
    unsigned short u[8];
    #pragma unroll
    for (int k = 0; k < 8; ++k) u[k] = xs[icg * 8 + k][xx];
    *(uint4*)(xT + (((size_t)bi * Hh + y) * Ww + (x0 + xx)) * Cin + icg * 8) = *(uint4*)u;
  }
}

// ---------- fused: conv1 (haloed, MFMA) -> h in LDS -> GEMV + AU + stats ----------
__global__ __launch_bounds__(256, 3) void fused_kernel(
    const unsigned short* __restrict__ xT, const unsigned short* __restrict__ Wbf,
    const unsigned short* __restrict__ Wtb, const unsigned short* __restrict__ Aub,
    const float* __restrict__ bc, const float* __restrict__ b_out,
    const float* __restrict__ b_aue, const float* __restrict__ lms,
    float* __restrict__ out) {
  __shared__ unsigned short sh[192 * HP];            // 50688 B
  const int tid = threadIdx.x;
  const int x0 = blockIdx.x * 16, y0 = blockIdx.y * 8, bi = blockIdx.z;

  // ---- stage x-patch: 12 rows x 20 cols x 8 ic-groups of 16 B ----
  for (int g = tid; g < 12 * 20 * 8; g += 256) {
    int icg = g & 7;
    int xc = (g >> 3) % 20;
    int xr = g / 160;
    int gy = y0 - 2 + xr, gx = x0 - 2 + xc;
    uint2 lo = make_uint2(0, 0), hi = make_uint2(0, 0);
    if ((unsigned)gy < Hh && (unsigned)gx < Ww) {
      uint4 v = *(const uint4*)(xT + (((size_t)bi * Hh + gy) * Ww + gx) * Cin + icg * 8);
      lo.x = v.x; lo.y = v.y; hi.x = v.z; hi.y = v.w;
    }
    int e = (xr * 20 + xc) * XP + icg * 8;
    *(uint2*)(&sh[e]) = lo;
    *(uint2*)(&sh[e + 4]) = hi;
  }
  __syncthreads();

  const int lane = tid & 63, wv = tid >> 6;
  const int n16 = lane & 15, q = lane >> 4;

  int xbase[3];
  #pragma unroll
  for (int s = 0; s < 3; ++s) {
    int px = (wv * 3 + s) * 16 + n16;               // 0..191 (>=180 garbage-safe)
    int pr = px / 18, pc = px % 18;
    xbase[s] = (pr * 20 + pc) * XP + q * 8;
  }

  f32x4 acc[3][8];                                   // [s=n-tile][mt=oc-tile]
  #pragma unroll
  for (int s = 0; s < 3; ++s)
    #pragma unroll
    for (int mt = 0; mt < 8; ++mt) acc[s][mt] = (f32x4){0.f, 0.f, 0.f, 0.f};

  // ---- phase 1 K-loop: 18 chunks, no barriers ----
  #pragma unroll
  for (int c = 0; c < 18; ++c) {
    const int tap = c >> 1, ichalf = (c & 1) * 32;
    const int dy = tap / 3, dx = tap % 3;
    const int xoff = (dy * 20 + dx) * XP + ichalf;
    bf16x8 xfr[3];
    #pragma unroll
    for (int s = 0; s < 3; ++s) {
      U8 t;
      int e = xbase[s] + xoff;
      t.u2[0] = *(const uint2*)(&sh[e]);
      t.u2[1] = *(const uint2*)(&sh[e + 4]);
      xfr[s] = t.v;
    }
    #pragma unroll
    for (int mh = 0; mh < 2; ++mh) {
      bf16x8 wfr[4];
      const unsigned short* wb = Wbf + ((size_t)(c * 8 + mh * 4) * 64 + lane) * 8;
      #pragma unroll
      for (int i4 = 0; i4 < 4; ++i4)
        wfr[i4] = ((const U8*)(wb + i4 * 512))->v;
      #pragma unroll
      for (int s = 0; s < 3; ++s)
        #pragma unroll
        for (int i4 = 0; i4 < 4; ++i4)
          acc[s][mh * 4 + i4] =
            __builtin_amdgcn_mfma_f32_16x16x32_bf16(wfr[i4], xfr[s], acc[s][mh * 4 + i4], 0, 0, 0);
    }
  }
  __syncthreads();                                   // x-view dead; reuse as h-view

  // ---- write h-patch to LDS: D n=px(lane n16), m=oc=mt*16+q*4+r ----
  // R6 BUG FIX: h-pixels outside the image must be ZERO (AU conv zero-pads h);
  // computed halo = conv(0-x) + bias = bias != 0. Zero the record when out-of-image.
  #pragma unroll
  for (int s = 0; s < 3; ++s) {
    const int px = (wv * 3 + s) * 16 + n16;
    const int pr = px / 18, pc = px % 18;
    const int gy = y0 - 1 + pr, gx = x0 - 1 + pc;
    const bool valid = ((unsigned)gy < Hh) && ((unsigned)gx < Ww);
    #pragma unroll
    for (int mt = 0; mt < 8; ++mt) {
      const int oc0 = mt * 16 + q * 4;
      const float4 b4 = *(const float4*)(bc + oc0);
      ushort4 o4;
      o4.x = valid ? f2bf(acc[s][mt][0] + b4.x) : (unsigned short)0;
      o4.y = valid ? f2bf(acc[s][mt][1] + b4.y) : (unsigned short)0;
      o4.z = valid ? f2bf(acc[s][mt][2] + b4.z) : (unsigned short)0;
      o4.w = valid ? f2bf(acc[s][mt][3] + b4.w) : (unsigned short)0;
      *(ushort4*)(&sh[px * HP + oc0]) = o4;
    }
  }
  __syncthreads();

  // ---- phase 2: GEMV + AU from LDS h-view ----
  f32x4 accG[2][4];
  f32x4 accA[2];
  #pragma unroll
  for (int nt = 0; nt < 2; ++nt) {
    accA[nt] = (f32x4){0.f, 0.f, 0.f, 0.f};
    #pragma unroll
    for (int mt = 0; mt < 4; ++mt) accG[nt][mt] = (f32x4){0.f, 0.f, 0.f, 0.f};
  }

  #pragma unroll
  for (int kc = 0; kc < 4; ++kc) {
    bf16x8 afr[4];
    #pragma unroll
    for (int mt = 0; mt < 4; ++mt)
      afr[mt] = ((const U8*)(Wtb + (size_t)(mt * 16 + n16) * C2c + kc * 32 + q * 8))->v;
    #pragma unroll
    for (int nt = 0; nt < 2; ++nt) {
      int e = (((wv * 2 + nt) + 1) * 18 + n16 + 1) * HP + kc * 32 + q * 8;
      U8 b;
      b.u2[0] = *(const uint2*)(&sh[e]);
      b.u2[1] = *(const uint2*)(&sh[e + 4]);
      #pragma unroll
      for (int mt = 0; mt < 4; ++mt)
        accG[nt][mt] = __builtin_amdgcn_mfma_f32_16x16x32_bf16(afr[mt], b.v, accG[nt][mt], 0, 0, 0);
    }
  }

  #pragma unroll
  for (int kc = 0; kc < 36; ++kc) {
    const int tap = kc >> 2, co = (kc & 3) * 32;
    const int dy = tap / 3, dx = tap % 3;
    bf16x8 afr = ((const U8*)(Aub + (size_t)n16 * 1152 + kc * 32 + q * 8))->v;
    #pragma unroll
    for (int nt = 0; nt < 2; ++nt) {
      int e = ((wv * 2 + nt + dy) * 18 + n16 + dx) * HP + co + q * 8;
      U8 b;
      b.u2[0] = *(const uint2*)(&sh[e]);
      b.u2[1] = *(const uint2*)(&sh[e + 4]);
      accA[nt] = __builtin_amdgcn_mfma_f32_16x16x32_bf16(afr, b.v, accA[nt], 0, 0, 0);
    }
  }

  // ---- stats: lane holds to = mt*16 + q*4 + r -> t=4mt+q, o=r ----
  const float b0 = b_out[0], b1 = b_out[1], b2 = b_out[2], b3 = b_out[3];
  const float ba = b_aue[q];
  const int px = x0 + n16;
  #pragma unroll
  for (int nt = 0; nt < 2; ++nt) {
    const int y = y0 + wv * 2 + nt;
    float th[4][4];
    #pragma unroll
    for (int mt = 0; mt < 4; ++mt) {
      #pragma unroll
      for (int r = 0; r < 4; ++r) {
        float bo = (r == 0) ? b0 : (r == 1) ? b1 : (r == 2) ? b2 : b3;
        float v = accG[nt][mt][r] + bo;
        float e = __expf(2.f * v);
        th[mt][r] = 1.f - 2.f / (e + 1.f);           // tanh(v)
      }
    }
    float mean_r[4], eu_r[4];
    #pragma unroll
    for (int r = 0; r < 4; ++r) {
      float s = th[0][r] + th[1][r] + th[2][r] + th[3][r];
      s += __shfl_xor(s, 16);
      s += __shfl_xor(s, 32);
      float m = s * (1.f / 16.f);
      float d0 = th[0][r] - m, d1 = th[1][r] - m, d2 = th[2][r] - m, d3 = th[3][r] - m;
      float vs = d0 * d0 + d1 * d1 + d2 * d2 + d3 * d3;
      vs += __shfl_xor(vs, 16);
      vs += __shfl_xor(vs, 32);
      mean_r[r] = m;
      eu_r[r] = vs * (1.f / 15.f);                   // ddof=1
    }
    float au_r[4];
    #pragma unroll
    for (int r = 0; r < 4; ++r) au_r[r] = __shfl(accA[nt][r], n16);

    float m_q  = (q == 0) ? mean_r[0] : (q == 1) ? mean_r[1] : (q == 2) ? mean_r[2] : mean_r[3];
    float eu_q = (q == 0) ? eu_r[0]   : (q == 1) ? eu_r[1]   : (q == 2) ? eu_r[2]   : eu_r[3];
    float au_q = (q == 0) ? au_r[0]   : (q == 1) ? au_r[1]   : (q == 2) ? au_r[2]   : au_r[3];
    au_q = 1.f / (1.f + __expf(-(au_q + ba)));
    size_t oidx = ((size_t)(bi * 4 + q)) * HW + (size_t)y * Ww + px;
    float lm = lms[oidx];
    out[oidx] = au_q;
    out[PLANE + oidx] = eu_q;
    out[2 * (size_t)PLANE + oidx] = m_q + lm;
  }
}

extern "C" void kernel_launch(void* const* d_in, const int* in_sizes, int n_in,
                              void* d_out, int out_size, void* d_ws, size_t ws_size,
                              hipStream_t stream) {
  const float* x      = (const float*)d_in[0];
  const float* lms    = (const float*)d_in[1];
  const float* W_conv = (const float*)d_in[2];
  const float* b_conv = (const float*)d_in[3];
  const float* W_out  = (const float*)d_in[4];
  const float* b_out  = (const float*)d_in[5];
  const float* W_aue  = (const float*)d_in[6];
  const float* b_aue  = (const float*)d_in[7];
  const float* masks  = (const float*)d_in[8];
  float* out = (float*)d_out;

  char* ws = (char*)d_ws;
  unsigned short* xT  = (unsigned short*)(ws + XT_OFF);
  unsigned short* Wbf = (unsigned short*)(ws + WBF_OFF);
  unsigned short* Wtb = (unsigned short*)(ws + WTB_OFF);
  unsigned short* Aub = (unsigned short*)(ws + AUB_OFF);

  prep_kernel<<<dim3(392), dim3(256), 0, stream>>>(W_out, masks, W_conv, W_aue, Wtb, Wbf, Aub);
  xt_kernel<<<dim3(4, 256, 4), dim3(256), 0, stream>>>(x, xT);
  fused_kernel<<<dim3(16, 32, 4), dim3(256), 0, stream>>>(xT, Wbf, Wtb, Aub, b_conv,
                                                          b_out, b_aue, lms, out);
}